// Round 2
// baseline (16703.040 us; speedup 1.0000x reference)
//
#include <hip/hip_runtime.h>
#include <cstdint>

typedef __bf16 bf16_t;
typedef __attribute__((ext_vector_type(8))) __bf16 bf16x8;
typedef __attribute__((ext_vector_type(4))) float f32x4;

#define TOKENS 26896
#define LLEN   1681
#define SDIM   41
#define EDIM   768
#define CHB    4                 // batches per chunk
#define CHT    (CHB * LLEN)      // tokens per chunk = 6724
#define NCH    4                 // chunks (16 batches total)

// ---------------- async global->LDS 16B ----------------
__device__ __forceinline__ void gload_lds16(const bf16_t* g, bf16_t* l) {
  auto gp = reinterpret_cast<const __attribute__((address_space(1))) char*>(
      reinterpret_cast<uintptr_t>(g));
  auto lp = reinterpret_cast<__attribute__((address_space(3))) char*>(
      reinterpret_cast<uintptr_t>(l));
  __builtin_amdgcn_global_load_lds(gp, lp, 16, 0, 0);
}

enum { EPI_T_POS = 0, EPI_BF16 = 1, EPI_ADD_T = 2, EPI_GELU = 3, EPI_F32 = 4 };

// C = A(MxK,bf16) @ Bt(NxK,bf16)^T ; 128x128 tile, 4 waves, 16x16x32 MFMA
template <int EPI>
__global__ __launch_bounds__(256) void gemm_kernel(
    const bf16_t* __restrict__ A, const bf16_t* __restrict__ Bt,
    const float* __restrict__ bias, float* __restrict__ fout,
    bf16_t* __restrict__ bout, const float* __restrict__ pos,
    int M, int N, int K)
{
  __shared__ bf16_t As[128 * 32];
  __shared__ bf16_t Bs[128 * 32];
  const int tid  = threadIdx.x;
  const int wave = tid >> 6;
  const int lane = tid & 63;
  const int row0 = blockIdx.x * 128;
  const int col0 = blockIdx.y * 128;
  const int wr = wave >> 1, wc = wave & 1;  // 2x2 waves of 64x64

  f32x4 acc[4][4] = {};

  const int srow  = lane >> 2;        // 0..15
  const int skoff = (lane & 3) * 8;   // element offset within 32-K

  const int nsteps = K >> 5;
  for (int kt = 0; kt < nsteps; ++kt) {
    const int k0 = kt << 5;
    #pragma unroll
    for (int i = 0; i < 2; ++i) {
      const int r = (i * 4 + wave) * 16 + srow;  // 0..127
      int arow = row0 + r; if (arow > M - 1) arow = M - 1;
      int brow = col0 + r; if (brow > N - 1) brow = N - 1;
      gload_lds16(A  + (size_t)arow * K + k0 + skoff, &As[r * 32 + skoff]);
      gload_lds16(Bt + (size_t)brow * K + k0 + skoff, &Bs[r * 32 + skoff]);
    }
    asm volatile("s_waitcnt vmcnt(0)" ::: "memory");
    __syncthreads();

    const int lrow = lane & 15;
    const int lk   = (lane >> 4) * 8;
    bf16x8 af[4], bfr[4];
    #pragma unroll
    for (int mi = 0; mi < 4; ++mi)
      af[mi] = *(const bf16x8*)&As[(wr * 64 + mi * 16 + lrow) * 32 + lk];
    #pragma unroll
    for (int ni = 0; ni < 4; ++ni)
      bfr[ni] = *(const bf16x8*)&Bs[(wc * 64 + ni * 16 + lrow) * 32 + lk];
    #pragma unroll
    for (int mi = 0; mi < 4; ++mi)
      #pragma unroll
      for (int ni = 0; ni < 4; ++ni)
        acc[mi][ni] = __builtin_amdgcn_mfma_f32_16x16x32_bf16(
            af[mi], bfr[ni], acc[mi][ni], 0, 0, 0);
    __syncthreads();
  }

  // epilogue: D row = (lane>>4)*4 + reg, col = lane&15  [m89-verified layout]
  const int lcol = lane & 15;
  const int rgrp = lane >> 4;
  #pragma unroll
  for (int mi = 0; mi < 4; ++mi) {
    #pragma unroll
    for (int ni = 0; ni < 4; ++ni) {
      const int col = col0 + wc * 64 + ni * 16 + lcol;
      if (col >= N) continue;
      const int rbase = row0 + wr * 64 + mi * 16 + rgrp * 4;
      float bv = 0.f;
      if constexpr (EPI != EPI_F32) bv = bias[col];
      #pragma unroll
      for (int r = 0; r < 4; ++r) {
        const int rr = rbase + r;
        if (rr >= M) continue;
        const float v = acc[mi][ni][r] + bv;
        const size_t o = (size_t)rr * N + col;
        if constexpr (EPI == EPI_T_POS) {
          const int l = rr % LLEN;   // chunk row_base is a multiple of LLEN
          fout[o] = v + pos[(size_t)l * N + col];
        } else if constexpr (EPI == EPI_BF16) {
          bout[o] = (bf16_t)v;
        } else if constexpr (EPI == EPI_ADD_T) {
          fout[o] += v;
        } else if constexpr (EPI == EPI_GELU) {
          const float gg = 0.5f * v * (1.f + erff(v * 0.70710678118654752f));
          bout[o] = (bf16_t)gg;
        } else {
          fout[o] = v;
        }
      }
    }
  }
}

// ---------------- LayerNorm: one wave per token, E=768 ----------------
__global__ __launch_bounds__(256) void ln_kernel(
    const float* __restrict__ t, const float* __restrict__ w,
    const float* __restrict__ b, bf16_t* __restrict__ y)
{
  const int token = blockIdx.x * 4 + (threadIdx.x >> 6);
  const int lane  = threadIdx.x & 63;
  const float* xp = t + (size_t)token * EDIM;
  float v[12];
  float s = 0.f;
  #pragma unroll
  for (int i = 0; i < 12; ++i) { v[i] = xp[lane + i * 64]; s += v[i]; }
  #pragma unroll
  for (int off = 32; off; off >>= 1) s += __shfl_xor(s, off);
  const float mu = s * (1.f / 768.f);
  float q = 0.f;
  #pragma unroll
  for (int i = 0; i < 12; ++i) { const float d = v[i] - mu; q += d * d; }
  #pragma unroll
  for (int off = 32; off; off >>= 1) q += __shfl_xor(q, off);
  const float rs = rsqrtf(q * (1.f / 768.f) + 1e-6f);
  bf16_t* yp = y + (size_t)token * EDIM;
  #pragma unroll
  for (int i = 0; i < 12; ++i) {
    const int e = lane + i * 64;
    yp[e] = (bf16_t)((v[i] - mu) * rs * w[e] + b[e]);
  }
}

// ---------------- row-wise attention: block per (b_local, s1, h) -----------
// qkv: chunk-local [CHT][2304]; o: chunk-offset [CHT][768]
__global__ __launch_bounds__(256) void attn_kernel(
    const bf16_t* __restrict__ qkv, bf16_t* __restrict__ o)
{
  const int blk = blockIdx.x;
  const int h  = blk % 12;
  const int bs = blk / 12;
  const int s1 = bs % SDIM;
  const int b  = bs / SDIM;   // local batch within chunk
  __shared__ float Qs[SDIM][65], Ks[SDIM][65], Vs[SDIM][65], Ps[SDIM][42];
  const int tid = threadIdx.x;
  const size_t base = ((size_t)b * LLEN + (size_t)s1 * SDIM);

  for (int idx = tid; idx < SDIM * 64; idx += 256) {
    const int m = idx >> 6, d = idx & 63;
    const bf16_t* p = qkv + (base + m) * 2304 + h * 64 + d;
    Qs[m][d] = (float)p[0];
    Ks[m][d] = (float)p[768];
    Vs[m][d] = (float)p[1536];
  }
  __syncthreads();

  for (int idx = tid; idx < SDIM * SDIM; idx += 256) {
    const int n = idx / SDIM, m = idx % SDIM;
    float s = 0.f;
    #pragma unroll
    for (int d = 0; d < 64; ++d) s += Qs[n][d] * Ks[m][d];
    Ps[n][m] = s * 0.125f;
  }
  __syncthreads();

  if (tid < SDIM) {
    float mx = -1e30f;
    for (int m = 0; m < SDIM; ++m) mx = fmaxf(mx, Ps[tid][m]);
    float sum = 0.f;
    for (int m = 0; m < SDIM; ++m) { const float e = __expf(Ps[tid][m] - mx); Ps[tid][m] = e; sum += e; }
    const float inv = 1.f / sum;
    for (int m = 0; m < SDIM; ++m) Ps[tid][m] *= inv;
  }
  __syncthreads();

  for (int idx = tid; idx < SDIM * 64; idx += 256) {
    const int n = idx >> 6, d = idx & 63;
    float s = 0.f;
    #pragma unroll
    for (int m = 0; m < SDIM; ++m) s += Ps[n][m] * Vs[m][d];
    o[(base + n) * EDIM + h * 64 + d] = (bf16_t)s;
  }
}

// ---------------- transpose fp32(KxN) -> bf16(NxK) ----------------
__global__ __launch_bounds__(256) void transpose_kernel(
    const float* __restrict__ in, bf16_t* __restrict__ out, int K, int N)
{
  __shared__ float tile[32][33];
  const int k0 = blockIdx.x * 32, n0 = blockIdx.y * 32;
  const int tx = threadIdx.x & 31, ty = threadIdx.x >> 5;
  #pragma unroll
  for (int i = 0; i < 32; i += 8) {
    const int k = k0 + ty + i, n = n0 + tx;
    if (k < K && n < N) tile[ty + i][tx] = in[(size_t)k * N + n];
  }
  __syncthreads();
  #pragma unroll
  for (int i = 0; i < 32; i += 8) {
    const int n = n0 + ty + i, k = k0 + tx;
    if (n < N && k < K) out[(size_t)n * K + k] = (bf16_t)tile[tx][ty + i];
  }
}

// ---------------- im2col for conv1 chunk (pad K 1200->1216) ----------------
__global__ __launch_bounds__(256) void im2col_kernel(
    const float* __restrict__ x, bf16_t* __restrict__ col, int tok0, int ntok)
{
  const size_t idx = (size_t)blockIdx.x * 256 + threadIdx.x;
  if (idx >= (size_t)ntok * 1216) return;
  const int kk = (int)(idx % 1216);
  const size_t tok = tok0 + idx / 1216;
  const int b = (int)(tok / LLEN), l = (int)(tok % LLEN);
  const int s1 = l / SDIM, s2 = l % SDIM;
  float v = 0.f;
  if (kk < 1200) {
    const int cin = kk / 100, r = kk % 100, ky = r / 10, kx = r % 10;
    const int iy = s1 - 5 + ky, ix = s2 - 5 + kx;
    if (iy >= 0 && iy < 40 && ix >= 0 && ix < 40)
      v = x[((size_t)(b * 12 + cin) * 40 + iy) * 40 + ix];
  }
  col[idx] = (bf16_t)v;
}

__global__ __launch_bounds__(256) void convw_kernel(
    const float* __restrict__ w, bf16_t* __restrict__ out)
{
  const int idx = blockIdx.x * 256 + threadIdx.x;  // 768*1216
  const int kk = idx % 1216, e = idx / 1216;
  const float v = (kk < 1200) ? w[(size_t)e * 1200 + kk] : 0.f;
  out[idx] = (bf16_t)v;
}

__global__ __launch_bounds__(256) void tconvw_kernel(
    const float* __restrict__ w, bf16_t* __restrict__ out)
{
  const int idx = blockIdx.x * 256 + threadIdx.x;  // 100*768
  const int e = idx % 768, tap = idx / 768;
  const int ky = tap / 10, kx = tap % 10;
  out[idx] = (bf16_t)w[(size_t)e * 100 + (9 - ky) * 10 + (9 - kx)];
}

// ---------------- final gather: out[b,y,x] = sum_tap g + bias ----------------
__global__ __launch_bounds__(256) void outconv_kernel(
    const float* __restrict__ g, const float* __restrict__ tb,
    float* __restrict__ out)
{
  const int idx = blockIdx.x * 256 + threadIdx.x;
  if (idx >= 16 * 40 * 40) return;
  const int x = idx % 40, y = (idx / 40) % 40, b = idx / 1600;
  float s = tb[0];
  #pragma unroll
  for (int ky = 0; ky < 10; ++ky) {
    const int ty_ = y - 4 + ky;
    if (ty_ < 0 || ty_ >= SDIM) continue;
    #pragma unroll
    for (int kx = 0; kx < 10; ++kx) {
      const int tx_ = x - 4 + kx;
      if (tx_ < 0 || tx_ >= SDIM) continue;
      s += g[((size_t)b * LLEN + ty_ * SDIM + tx_) * 100 + ky * 10 + kx];
    }
  }
  out[idx] = s;
}

extern "C" void kernel_launch(void* const* d_in, const int* in_sizes, int n_in,
                              void* d_out, int out_size, void* d_ws, size_t ws_size,
                              hipStream_t stream)
{
  const float* x       = (const float*)d_in[0];
  const float* conv_w  = (const float*)d_in[1];
  const float* conv_b  = (const float*)d_in[2];
  const float* pos     = (const float*)d_in[3];
  const float* ln1_w   = (const float*)d_in[4];
  const float* ln1_b   = (const float*)d_in[5];
  const float* qkv_w   = (const float*)d_in[6];
  const float* qkv_b   = (const float*)d_in[7];
  const float* proj_w  = (const float*)d_in[8];
  const float* proj_b  = (const float*)d_in[9];
  const float* ln2_w   = (const float*)d_in[10];
  const float* ln2_b   = (const float*)d_in[11];
  const float* fc1_w   = (const float*)d_in[12];
  const float* fc1_b   = (const float*)d_in[13];
  const float* fc2_w   = (const float*)d_in[14];
  const float* fc2_b   = (const float*)d_in[15];
  const float* lnf_w   = (const float*)d_in[16];
  const float* lnf_b   = (const float*)d_in[17];
  const float* tconv_w = (const float*)d_in[18];
  const float* tconv_b = (const float*)d_in[19];
  float* out = (float*)d_out;

  // ---- workspace layout (~179.4 MB total) ----
  char* p = (char*)d_ws;
  auto alloc = [&](size_t bytes) {
    char* r = p;
    p += (bytes + 255) & ~(size_t)255;
    return r;
  };
  // per-layer transposed weights, reused each layer (also holds Wc / Wt)
  bf16_t* wbuf = (bf16_t*)alloc((size_t)768 * 9216 * 2);        // 14.16 MB
  float*  t    = (float*)alloc((size_t)TOKENS * EDIM * 4);      // 82.58 MB
  bf16_t* ybuf = (bf16_t*)alloc((size_t)TOKENS * EDIM * 2);     // 41.31 MB
  bf16_t* hbuf = (bf16_t*)alloc((size_t)CHT * 3072 * 2);        // 41.31 MB

  bf16_t* Wq = wbuf;                         // 2304*768
  bf16_t* Wp = Wq + (size_t)2304 * 768;      // 768*768
  bf16_t* W1 = Wp + (size_t)768 * 768;       // 3072*768
  bf16_t* W2 = W1 + (size_t)3072 * 768;      // 768*3072

  auto launch_gemm = [&](int epi, const bf16_t* A, const bf16_t* Bt,
                         const float* bias, float* fo, bf16_t* bo,
                         const float* pe, int M, int N, int K) {
    dim3 grid((M + 127) / 128, (N + 127) / 128);
    switch (epi) {
      case EPI_T_POS: gemm_kernel<EPI_T_POS><<<grid, 256, 0, stream>>>(A, Bt, bias, fo, bo, pe, M, N, K); break;
      case EPI_BF16:  gemm_kernel<EPI_BF16 ><<<grid, 256, 0, stream>>>(A, Bt, bias, fo, bo, pe, M, N, K); break;
      case EPI_ADD_T: gemm_kernel<EPI_ADD_T><<<grid, 256, 0, stream>>>(A, Bt, bias, fo, bo, pe, M, N, K); break;
      case EPI_GELU:  gemm_kernel<EPI_GELU ><<<grid, 256, 0, stream>>>(A, Bt, bias, fo, bo, pe, M, N, K); break;
      default:        gemm_kernel<EPI_F32  ><<<grid, 256, 0, stream>>>(A, Bt, bias, fo, bo, pe, M, N, K); break;
    }
  };

  // ---- conv1 as chunked im2col GEMM -> t (+bias +pos_embed) ----
  convw_kernel<<<(768 * 1216) / 256, 256, 0, stream>>>(conv_w, wbuf);
  for (int c = 0; c < NCH; ++c) {
    const int tok0 = c * CHT;
    im2col_kernel<<<(unsigned)(((size_t)CHT * 1216 + 255) / 256), 256, 0, stream>>>(x, hbuf, tok0, CHT);
    launch_gemm(EPI_T_POS, hbuf, wbuf, conv_b, t + (size_t)tok0 * EDIM, nullptr, pos, CHT, EDIM, 1216);
  }

  // ---- transformer layers ----
  for (int i = 0; i < 12; ++i) {
    // per-layer weight transposes into wbuf
    transpose_kernel<<<dim3(24, 72), 256, 0, stream>>>(qkv_w + (size_t)i * 768 * 2304, Wq, 768, 2304);
    transpose_kernel<<<dim3(24, 24), 256, 0, stream>>>(proj_w + (size_t)i * 768 * 768, Wp, 768, 768);
    transpose_kernel<<<dim3(24, 96), 256, 0, stream>>>(fc1_w + (size_t)i * 768 * 3072, W1, 768, 3072);
    transpose_kernel<<<dim3(96, 24), 256, 0, stream>>>(fc2_w + (size_t)i * 3072 * 768, W2, 3072, 768);

    ln_kernel<<<TOKENS / 4, 256, 0, stream>>>(t, ln1_w + i * EDIM, ln1_b + i * EDIM, ybuf);
    for (int c = 0; c < NCH; ++c) {
      const size_t ro = (size_t)c * CHT;
      launch_gemm(EPI_BF16, ybuf + ro * EDIM, Wq, qkv_b + i * 2304, nullptr, hbuf, nullptr, CHT, 2304, 768);
      attn_kernel<<<CHB * SDIM * 12, 256, 0, stream>>>(hbuf, ybuf + ro * EDIM);
    }
    launch_gemm(EPI_ADD_T, ybuf, Wp, proj_b + i * EDIM, t, nullptr, nullptr, TOKENS, EDIM, 768);

    ln_kernel<<<TOKENS / 4, 256, 0, stream>>>(t, ln2_w + i * EDIM, ln2_b + i * EDIM, ybuf);
    for (int c = 0; c < NCH; ++c) {
      const size_t ro = (size_t)c * CHT;
      launch_gemm(EPI_GELU, ybuf + ro * EDIM, W1, fc1_b + i * 3072, nullptr, hbuf, nullptr, CHT, 3072, 768);
      launch_gemm(EPI_ADD_T, hbuf, W2, fc2_b + i * EDIM, t + ro * EDIM, nullptr, nullptr, CHT, EDIM, 3072);
    }
  }

  // ---- final LN + tconv head ----
  ln_kernel<<<TOKENS / 4, 256, 0, stream>>>(t, lnf_w, lnf_b, ybuf);
  tconvw_kernel<<<(100 * 768) / 256, 256, 0, stream>>>(tconv_w, wbuf);
  launch_gemm(EPI_F32, ybuf, wbuf, nullptr, (float*)hbuf, nullptr, nullptr, TOKENS, 100, 768);
  outconv_kernel<<<100, 256, 0, stream>>>((const float*)hbuf, tconv_b, out);
}

// Round 3
// 14843.340 us; speedup vs baseline: 1.1253x; 1.1253x over previous
//
#include <hip/hip_runtime.h>
#include <cstdint>

typedef __bf16 bf16_t;
typedef __attribute__((ext_vector_type(8))) __bf16 bf16x8;
typedef __attribute__((ext_vector_type(4))) float f32x4;

#define TOKENS 26896
#define LLEN   1681
#define SDIM   41
#define EDIM   768

// ---------------- async global->LDS 16B ----------------
__device__ __forceinline__ void gload_lds16(const bf16_t* g, bf16_t* l) {
  auto gp = reinterpret_cast<const __attribute__((address_space(1))) char*>(
      reinterpret_cast<uintptr_t>(g));
  auto lp = reinterpret_cast<__attribute__((address_space(3))) char*>(
      reinterpret_cast<uintptr_t>(l));
  __builtin_amdgcn_global_load_lds(gp, lp, 16, 0, 0);
}

enum { EPI_T_POS = 0, EPI_BF16 = 1, EPI_ADD_T = 2, EPI_GELU = 3, EPI_F32 = 4 };

// ============================================================================
// gemm2: C = A(MxK,bf16) @ Bt(NxK,bf16)^T
// Tile BMT x 256, BK=32, 8 waves (512 thr), wave-tile (BMT/2) x 64.
// Ring of 4 LDS buffers, stage 3 tiles ahead, counted vmcnt, reg-frag dbuf,
// T2 XOR swizzle (both sides), T5 setprio, T1 XCD swizzle on block id.
// ============================================================================
template <int BMT, int EPI>
__global__ __launch_bounds__(512, 2) void gemm2_kernel(
    const bf16_t* __restrict__ A, const bf16_t* __restrict__ Bt,
    const float* __restrict__ bias, float* __restrict__ fout,
    bf16_t* __restrict__ bout, const float* __restrict__ pos,
    int M, int N, int K, int mtiles)
{
  constexpr int MW    = BMT / 32;          // m-frags per wave (4 or 8)
  constexpr int APASS = BMT / 128;         // A staging passes (1 or 2)
  constexpr int LPT   = APASS + 2;         // vmem loads per thread per tile
  constexpr int SLOT  = (BMT + 256) * 32;  // bf16 elems per ring slot
  extern __shared__ bf16_t lds[];

  const int tid = threadIdx.x, wave = tid >> 6, lane = tid & 63;
  const int wr = wave >> 2, wc = wave & 3;

  // T1: bijective XCD swizzle (m204)
  int id = blockIdx.x;
  {
    const int nwg = mtiles * (N >> 8) + ((N & 255) ? mtiles : 0);
    const int q = nwg >> 3, r = nwg & 7;
    const int xcd = id & 7, idx = id >> 3;
    id = (xcd < r ? xcd * (q + 1) : r * (q + 1) + (xcd - r) * q) + idx;
  }
  const int row0 = (id % mtiles) * BMT;
  const int col0 = (id / mtiles) * 256;
  const int NT = K >> 5;

  const int srow  = tid >> 2;   // 0..127
  const int sslot = tid & 3;

  auto stage = [&](int slot, int kt) {
    bf16_t* base = &lds[slot * SLOT];
    const int k0 = kt << 5;
    #pragma unroll
    for (int p = 0; p < APASS; ++p) {
      const int r = p * 128 + srow;
      int grow = row0 + r; if (grow > M - 1) grow = M - 1;
      const int gk = k0 + ((sslot ^ ((r >> 1) & 3)) << 3);  // pre-swizzled src
      gload_lds16(A + (size_t)grow * K + gk, base + r * 32 + sslot * 8);
    }
    bf16_t* bbase = base + BMT * 32;
    #pragma unroll
    for (int p = 0; p < 2; ++p) {
      const int r = p * 128 + srow;
      int grow = col0 + r; if (grow > N - 1) grow = N - 1;
      const int gk = k0 + ((sslot ^ ((r >> 1) & 3)) << 3);
      gload_lds16(Bt + (size_t)grow * K + gk, bbase + r * 32 + sslot * 8);
    }
  };

  const int l15 = lane & 15, l4 = lane >> 4;
  auto ldfrag = [&](int slot, bf16x8 (&fa)[MW], bf16x8 (&fb)[4]) {
    const bf16_t* base = &lds[slot * SLOT];
    #pragma unroll
    for (int m = 0; m < MW; ++m) {
      const int r = wr * (BMT / 2) + m * 16 + l15;
      fa[m] = *(const bf16x8*)(base + r * 32 + ((l4 ^ ((r >> 1) & 3)) << 3));
    }
    const bf16_t* bbase = base + BMT * 32;
    #pragma unroll
    for (int n = 0; n < 4; ++n) {
      const int r = wc * 64 + n * 16 + l15;
      fb[n] = *(const bf16x8*)(bbase + r * 32 + ((l4 ^ ((r >> 1) & 3)) << 3));
    }
  };

  f32x4 acc[MW][4] = {};
  auto domfma = [&](bf16x8 (&fa)[MW], bf16x8 (&fb)[4]) {
    __builtin_amdgcn_s_setprio(1);
    #pragma unroll
    for (int m = 0; m < MW; ++m)
      #pragma unroll
      for (int n = 0; n < 4; ++n)
        acc[m][n] = __builtin_amdgcn_mfma_f32_16x16x32_bf16(fa[m], fb[n], acc[m][n], 0, 0, 0);
    __builtin_amdgcn_s_setprio(0);
  };

  #define VMCNT_LPT() do { \
    if constexpr (LPT == 4) asm volatile("s_waitcnt vmcnt(4)" ::: "memory"); \
    else                    asm volatile("s_waitcnt vmcnt(3)" ::: "memory"); \
  } while (0)

  bf16x8 a0[MW], b0[4], a1[MW], b1[4];

  // prologue: stage tiles 0,1,2; retire 0,1; publish; read frags(0)
  stage(0, 0); stage(1, 1); stage(2, 2);
  VMCNT_LPT();
  __syncthreads();
  ldfrag(0, a0, b0);

  for (int kt = 0; kt < NT; kt += 2) {
    // ---- tile kt (cur = set0) ----
    if (kt + 3 < NT) stage((kt + 3) & 3, kt + 3);
    if (kt + 1 < NT) ldfrag((kt + 1) & 3, a1, b1);
    domfma(a0, b0);
    if (kt + 3 < NT) { VMCNT_LPT(); }
    else             { asm volatile("s_waitcnt vmcnt(0)" ::: "memory"); }
    __syncthreads();
    // ---- tile kt+1 (cur = set1) ----
    if (kt + 4 < NT) stage((kt + 4) & 3, kt + 4);
    if (kt + 2 < NT) ldfrag((kt + 2) & 3, a0, b0);
    domfma(a1, b1);
    if (kt + 4 < NT) { VMCNT_LPT(); }
    else             { asm volatile("s_waitcnt vmcnt(0)" ::: "memory"); }
    __syncthreads();
  }
  #undef VMCNT_LPT

  // epilogue: D row = (lane>>4)*4 + r, col = lane&15 (m89 layout)
  const int rgrp = lane >> 4;
  #pragma unroll
  for (int m = 0; m < MW; ++m) {
    #pragma unroll
    for (int n = 0; n < 4; ++n) {
      const int col = col0 + wc * 64 + n * 16 + l15;
      if (col >= N) continue;
      const int rbase = row0 + wr * (BMT / 2) + m * 16 + rgrp * 4;
      float bv = 0.f;
      if constexpr (EPI != EPI_F32) bv = bias[col];
      #pragma unroll
      for (int r = 0; r < 4; ++r) {
        const int rr = rbase + r;
        if (rr >= M) continue;
        const float v = acc[m][n][r] + bv;
        const size_t o = (size_t)rr * N + col;
        if constexpr (EPI == EPI_T_POS) {
          const int l = rr % LLEN;
          fout[o] = v + pos[(size_t)l * N + col];
        } else if constexpr (EPI == EPI_BF16) {
          bout[o] = (bf16_t)v;
        } else if constexpr (EPI == EPI_ADD_T) {
          fout[o] += v;
        } else if constexpr (EPI == EPI_GELU) {
          const float gg = 0.5f * v * (1.f + erff(v * 0.70710678118654752f));
          bout[o] = (bf16_t)gg;
        } else {
          fout[o] = v;
        }
      }
    }
  }
}

// ---------------- old 128x128 kernel, F32 epilogue (head GEMM, N=100) -------
__global__ __launch_bounds__(256) void gemm128_f32(
    const bf16_t* __restrict__ A, const bf16_t* __restrict__ Bt,
    float* __restrict__ fout, int M, int N, int K)
{
  __shared__ bf16_t As[128 * 32];
  __shared__ bf16_t Bs[128 * 32];
  const int tid = threadIdx.x, wave = tid >> 6, lane = tid & 63;
  const int row0 = blockIdx.x * 128, col0 = blockIdx.y * 128;
  const int wr = wave >> 1, wc = wave & 1;
  f32x4 acc[4][4] = {};
  const int srow = lane >> 2, skoff = (lane & 3) * 8;
  const int nsteps = K >> 5;
  for (int kt = 0; kt < nsteps; ++kt) {
    const int k0 = kt << 5;
    #pragma unroll
    for (int i = 0; i < 2; ++i) {
      const int r = (i * 4 + wave) * 16 + srow;
      int arow = row0 + r; if (arow > M - 1) arow = M - 1;
      int brow = col0 + r; if (brow > N - 1) brow = N - 1;
      gload_lds16(A  + (size_t)arow * K + k0 + skoff, &As[r * 32 + skoff]);
      gload_lds16(Bt + (size_t)brow * K + k0 + skoff, &Bs[r * 32 + skoff]);
    }
    asm volatile("s_waitcnt vmcnt(0)" ::: "memory");
    __syncthreads();
    const int lrow = lane & 15, lk = (lane >> 4) * 8;
    bf16x8 af[4], bfr[4];
    #pragma unroll
    for (int mi = 0; mi < 4; ++mi)
      af[mi] = *(const bf16x8*)&As[(wr * 64 + mi * 16 + lrow) * 32 + lk];
    #pragma unroll
    for (int ni = 0; ni < 4; ++ni)
      bfr[ni] = *(const bf16x8*)&Bs[(wc * 64 + ni * 16 + lrow) * 32 + lk];
    #pragma unroll
    for (int mi = 0; mi < 4; ++mi)
      #pragma unroll
      for (int ni = 0; ni < 4; ++ni)
        acc[mi][ni] = __builtin_amdgcn_mfma_f32_16x16x32_bf16(af[mi], bfr[ni], acc[mi][ni], 0, 0, 0);
    __syncthreads();
  }
  const int lcol = lane & 15, rgrp = lane >> 4;
  #pragma unroll
  for (int mi = 0; mi < 4; ++mi)
    #pragma unroll
    for (int ni = 0; ni < 4; ++ni) {
      const int col = col0 + wc * 64 + ni * 16 + lcol;
      if (col >= N) continue;
      const int rbase = row0 + wr * 64 + mi * 16 + rgrp * 4;
      #pragma unroll
      for (int r = 0; r < 4; ++r) {
        const int rr = rbase + r;
        if (rr >= M) continue;
        fout[(size_t)rr * N + col] = acc[mi][ni][r];
      }
    }
}

// ---------------- LayerNorm: one wave per token, E=768 ----------------
__global__ __launch_bounds__(256) void ln_kernel(
    const float* __restrict__ t, const float* __restrict__ w,
    const float* __restrict__ b, bf16_t* __restrict__ y)
{
  const int token = blockIdx.x * 4 + (threadIdx.x >> 6);
  const int lane  = threadIdx.x & 63;
  const float* xp = t + (size_t)token * EDIM;
  float v[12];
  float s = 0.f;
  #pragma unroll
  for (int i = 0; i < 12; ++i) { v[i] = xp[lane + i * 64]; s += v[i]; }
  #pragma unroll
  for (int off = 32; off; off >>= 1) s += __shfl_xor(s, off);
  const float mu = s * (1.f / 768.f);
  float q = 0.f;
  #pragma unroll
  for (int i = 0; i < 12; ++i) { const float d = v[i] - mu; q += d * d; }
  #pragma unroll
  for (int off = 32; off; off >>= 1) q += __shfl_xor(q, off);
  const float rs = rsqrtf(q * (1.f / 768.f) + 1e-6f);
  bf16_t* yp = y + (size_t)token * EDIM;
  #pragma unroll
  for (int i = 0; i < 12; ++i) {
    const int e = lane + i * 64;
    yp[e] = (bf16_t)((v[i] - mu) * rs * w[e] + b[e]);
  }
}

// ---------------- row-wise attention: block per (b_local, s1, h) -----------
__global__ __launch_bounds__(256) void attn_kernel(
    const bf16_t* __restrict__ qkv, bf16_t* __restrict__ o)
{
  const int blk = blockIdx.x;
  const int h  = blk % 12;
  const int bs = blk / 12;
  const int s1 = bs % SDIM;
  const int b  = bs / SDIM;
  __shared__ float Qs[SDIM][65], Ks[SDIM][65], Vs[SDIM][65], Ps[SDIM][42];
  const int tid = threadIdx.x;
  const size_t base = ((size_t)b * LLEN + (size_t)s1 * SDIM);

  for (int idx = tid; idx < SDIM * 64; idx += 256) {
    const int m = idx >> 6, d = idx & 63;
    const bf16_t* p = qkv + (base + m) * 2304 + h * 64 + d;
    Qs[m][d] = (float)p[0];
    Ks[m][d] = (float)p[768];
    Vs[m][d] = (float)p[1536];
  }
  __syncthreads();

  for (int idx = tid; idx < SDIM * SDIM; idx += 256) {
    const int n = idx / SDIM, m = idx % SDIM;
    float s = 0.f;
    #pragma unroll
    for (int d = 0; d < 64; ++d) s += Qs[n][d] * Ks[m][d];
    Ps[n][m] = s * 0.125f;
  }
  __syncthreads();

  if (tid < SDIM) {
    float mx = -1e30f;
    for (int m = 0; m < SDIM; ++m) mx = fmaxf(mx, Ps[tid][m]);
    float sum = 0.f;
    for (int m = 0; m < SDIM; ++m) { const float e = __expf(Ps[tid][m] - mx); Ps[tid][m] = e; sum += e; }
    const float inv = 1.f / sum;
    for (int m = 0; m < SDIM; ++m) Ps[tid][m] *= inv;
  }
  __syncthreads();

  for (int idx = tid; idx < SDIM * 64; idx += 256) {
    const int n = idx >> 6, d = idx & 63;
    float s = 0.f;
    #pragma unroll
    for (int m = 0; m < SDIM; ++m) s += Ps[n][m] * Vs[m][d];
    o[(base + n) * EDIM + h * 64 + d] = (bf16_t)s;
  }
}

// ---------------- transpose fp32(KxN) -> bf16(NxK) ----------------
__global__ __launch_bounds__(256) void transpose_kernel(
    const float* __restrict__ in, bf16_t* __restrict__ out, int K, int N)
{
  __shared__ float tile[32][33];
  const int k0 = blockIdx.x * 32, n0 = blockIdx.y * 32;
  const int tx = threadIdx.x & 31, ty = threadIdx.x >> 5;
  #pragma unroll
  for (int i = 0; i < 32; i += 8) {
    const int k = k0 + ty + i, n = n0 + tx;
    if (k < K && n < N) tile[ty + i][tx] = in[(size_t)k * N + n];
  }
  __syncthreads();
  #pragma unroll
  for (int i = 0; i < 32; i += 8) {
    const int n = n0 + ty + i, k = k0 + tx;
    if (n < N && k < K) out[(size_t)n * K + k] = (bf16_t)tile[tx][ty + i];
  }
}

// ---------------- im2col for conv1 chunk (pad K 1200->1216) ----------------
__global__ __launch_bounds__(256) void im2col_kernel(
    const float* __restrict__ x, bf16_t* __restrict__ col, int tok0, int ntok)
{
  const size_t idx = (size_t)blockIdx.x * 256 + threadIdx.x;
  if (idx >= (size_t)ntok * 1216) return;
  const int kk = (int)(idx % 1216);
  const size_t tok = tok0 + idx / 1216;
  const int b = (int)(tok / LLEN), l = (int)(tok % LLEN);
  const int s1 = l / SDIM, s2 = l % SDIM;
  float v = 0.f;
  if (kk < 1200) {
    const int cin = kk / 100, r = kk % 100, ky = r / 10, kx = r % 10;
    const int iy = s1 - 5 + ky, ix = s2 - 5 + kx;
    if (iy >= 0 && iy < 40 && ix >= 0 && ix < 40)
      v = x[((size_t)(b * 12 + cin) * 40 + iy) * 40 + ix];
  }
  col[idx] = (bf16_t)v;
}

__global__ __launch_bounds__(256) void convw_kernel(
    const float* __restrict__ w, bf16_t* __restrict__ out)
{
  const int idx = blockIdx.x * 256 + threadIdx.x;
  const int kk = idx % 1216, e = idx / 1216;
  const float v = (kk < 1200) ? w[(size_t)e * 1200 + kk] : 0.f;
  out[idx] = (bf16_t)v;
}

__global__ __launch_bounds__(256) void tconvw_kernel(
    const float* __restrict__ w, bf16_t* __restrict__ out)
{
  const int idx = blockIdx.x * 256 + threadIdx.x;  // 100*768
  const int e = idx % 768, tap = idx / 768;
  const int ky = tap / 10, kx = tap % 10;
  out[idx] = (bf16_t)w[(size_t)e * 100 + (9 - ky) * 10 + (9 - kx)];
}

// ---------------- final gather ----------------
__global__ __launch_bounds__(256) void outconv_kernel(
    const float* __restrict__ g, const float* __restrict__ tb,
    float* __restrict__ out)
{
  const int idx = blockIdx.x * 256 + threadIdx.x;
  if (idx >= 16 * 40 * 40) return;
  const int x = idx % 40, y = (idx / 40) % 40, b = idx / 1600;
  float s = tb[0];
  #pragma unroll
  for (int ky = 0; ky < 10; ++ky) {
    const int ty_ = y - 4 + ky;
    if (ty_ < 0 || ty_ >= SDIM) continue;
    #pragma unroll
    for (int kx = 0; kx < 10; ++kx) {
      const int tx_ = x - 4 + kx;
      if (tx_ < 0 || tx_ >= SDIM) continue;
      s += g[((size_t)b * LLEN + ty_ * SDIM + tx_) * 100 + ky * 10 + kx];
    }
  }
  out[idx] = s;
}

// ============================================================================
extern "C" void kernel_launch(void* const* d_in, const int* in_sizes, int n_in,
                              void* d_out, int out_size, void* d_ws, size_t ws_size,
                              hipStream_t stream)
{
  const float* x       = (const float*)d_in[0];
  const float* conv_w  = (const float*)d_in[1];
  const float* conv_b  = (const float*)d_in[2];
  const float* pos     = (const float*)d_in[3];
  const float* ln1_w   = (const float*)d_in[4];
  const float* ln1_b   = (const float*)d_in[5];
  const float* qkv_w   = (const float*)d_in[6];
  const float* qkv_b   = (const float*)d_in[7];
  const float* proj_w  = (const float*)d_in[8];
  const float* proj_b  = (const float*)d_in[9];
  const float* ln2_w   = (const float*)d_in[10];
  const float* ln2_b   = (const float*)d_in[11];
  const float* fc1_w   = (const float*)d_in[12];
  const float* fc1_b   = (const float*)d_in[13];
  const float* fc2_w   = (const float*)d_in[14];
  const float* fc2_b   = (const float*)d_in[15];
  const float* lnf_w   = (const float*)d_in[16];
  const float* lnf_b   = (const float*)d_in[17];
  const float* tconv_w = (const float*)d_in[18];
  const float* tconv_b = (const float*)d_in[19];
  float* out = (float*)d_out;

  // ---- dynamic-LDS attributes for >64KB kernels (host-side, capture-safe) ----
  constexpr int LDS128 = (128 + 256) * 32 * 2 * 4;  // 96 KB
  constexpr int LDS256 = (256 + 256) * 32 * 2 * 4;  // 128 KB
  hipFuncSetAttribute((const void*)gemm2_kernel<128, EPI_T_POS>, hipFuncAttributeMaxDynamicSharedMemorySize, LDS128);
  hipFuncSetAttribute((const void*)gemm2_kernel<128, EPI_ADD_T>, hipFuncAttributeMaxDynamicSharedMemorySize, LDS128);
  hipFuncSetAttribute((const void*)gemm2_kernel<128, EPI_GELU >, hipFuncAttributeMaxDynamicSharedMemorySize, LDS128);
  hipFuncSetAttribute((const void*)gemm2_kernel<256, EPI_BF16 >, hipFuncAttributeMaxDynamicSharedMemorySize, LDS256);

  // ---- workspace: pick chunking from ws_size ----
  const size_t need2 = 14155776UL + 82624512UL + 41312256UL + 82624512UL + 2048UL;
  const int nch = (ws_size >= need2) ? 2 : 4;
  const int cht = TOKENS / nch;          // 13448 or 6724

  char* p = (char*)d_ws;
  auto alloc = [&](size_t bytes) {
    char* r = p;
    p += (bytes + 255) & ~(size_t)255;
    return r;
  };
  bf16_t* wbuf = (bf16_t*)alloc((size_t)768 * 9216 * 2);
  float*  t    = (float*)alloc((size_t)TOKENS * EDIM * 4);
  bf16_t* ybuf = (bf16_t*)alloc((size_t)TOKENS * EDIM * 2);
  bf16_t* hbuf = (bf16_t*)alloc((size_t)cht * 3072 * 2);

  bf16_t* Wq = wbuf;
  bf16_t* Wp = Wq + (size_t)2304 * 768;
  bf16_t* W1 = Wp + (size_t)768 * 768;
  bf16_t* W2 = W1 + (size_t)3072 * 768;

  auto g2 = [&](int bmt, int epi, const bf16_t* A, const bf16_t* Bt,
                const float* bias, float* fo, bf16_t* bo, const float* pe,
                int M, int N, int K) {
    const int mtiles = (M + bmt - 1) / bmt;
    const int nwg = mtiles * (N / 256);
    const int lds = (bmt == 128) ? LDS128 : LDS256;
    if (bmt == 128) {
      switch (epi) {
        case EPI_T_POS: gemm2_kernel<128, EPI_T_POS><<<nwg, 512, lds, stream>>>(A, Bt, bias, fo, bo, pe, M, N, K, mtiles); break;
        case EPI_ADD_T: gemm2_kernel<128, EPI_ADD_T><<<nwg, 512, lds, stream>>>(A, Bt, bias, fo, bo, pe, M, N, K, mtiles); break;
        default:        gemm2_kernel<128, EPI_GELU ><<<nwg, 512, lds, stream>>>(A, Bt, bias, fo, bo, pe, M, N, K, mtiles); break;
      }
    } else {
      gemm2_kernel<256, EPI_BF16><<<nwg, 512, lds, stream>>>(A, Bt, bias, fo, bo, pe, M, N, K, mtiles);
    }
  };

  // ---- conv1 as chunked im2col GEMM -> t (+bias +pos_embed) ----
  convw_kernel<<<(768 * 1216) / 256, 256, 0, stream>>>(conv_w, wbuf);
  for (int c = 0; c < nch; ++c) {
    const int tok0 = c * cht;
    im2col_kernel<<<(unsigned)(((size_t)cht * 1216 + 255) / 256), 256, 0, stream>>>(x, hbuf, tok0, cht);
    g2(128, EPI_T_POS, hbuf, wbuf, conv_b, t + (size_t)tok0 * EDIM, nullptr, pos, cht, EDIM, 1216);
  }

  // ---- transformer layers ----
  for (int i = 0; i < 12; ++i) {
    transpose_kernel<<<dim3(24, 72), 256, 0, stream>>>(qkv_w + (size_t)i * 768 * 2304, Wq, 768, 2304);
    transpose_kernel<<<dim3(24, 24), 256, 0, stream>>>(proj_w + (size_t)i * 768 * 768, Wp, 768, 768);
    transpose_kernel<<<dim3(24, 96), 256, 0, stream>>>(fc1_w + (size_t)i * 768 * 3072, W1, 768, 3072);
    transpose_kernel<<<dim3(96, 24), 256, 0, stream>>>(fc2_w + (size_t)i * 3072 * 768, W2, 3072, 768);

    ln_kernel<<<TOKENS / 4, 256, 0, stream>>>(t, ln1_w + i * EDIM, ln1_b + i * EDIM, ybuf);
    for (int c = 0; c < nch; ++c) {
      const size_t ro = (size_t)c * cht;
      g2(256, EPI_BF16, ybuf + ro * EDIM, Wq, qkv_b + i * 2304, nullptr, hbuf, nullptr, cht, 2304, 768);
      attn_kernel<<<(TOKENS / LLEN / nch) * SDIM * 12, 256, 0, stream>>>(hbuf, ybuf + ro * EDIM);
    }
    g2(128, EPI_ADD_T, ybuf, Wp, proj_b + i * EDIM, t, nullptr, nullptr, TOKENS, EDIM, 768);

    ln_kernel<<<TOKENS / 4, 256, 0, stream>>>(t, ln2_w + i * EDIM, ln2_b + i * EDIM, ybuf);
    for (int c = 0; c < nch; ++c) {
      const size_t ro = (size_t)c * cht;
      g2(128, EPI_GELU, ybuf + ro * EDIM, W1, fc1_b + i * 3072, nullptr, hbuf, nullptr, cht, 3072, 768);
      g2(128, EPI_ADD_T, hbuf, W2, fc2_b + i * EDIM, t + ro * EDIM, nullptr, nullptr, cht, EDIM, 3072);
    }
  }

  // ---- final LN + tconv head ----
  ln_kernel<<<TOKENS / 4, 256, 0, stream>>>(t, lnf_w, lnf_b, ybuf);
  tconvw_kernel<<<(100 * 768) / 256, 256, 0, stream>>>(tconv_w, wbuf);
  gemm128_f32<<<dim3((TOKENS + 127) / 128, 1), 256, 0, stream>>>(ybuf, wbuf, (float*)hbuf, TOKENS, 100, 768);
  outconv_kernel<<<100, 256, 0, stream>>>((const float*)hbuf, tconv_b, out);
}

// Round 4
// 14064.581 us; speedup vs baseline: 1.1876x; 1.0554x over previous
//
#include <hip/hip_runtime.h>
#include <cstdint>

typedef __bf16 bf16_t;
typedef __attribute__((ext_vector_type(8))) __bf16 bf16x8;
typedef __attribute__((ext_vector_type(4))) float f32x4;

#define TOKENS 26896
#define LLEN   1681
#define SDIM   41
#define EDIM   768

// ---------------- async global->LDS 16B ----------------
__device__ __forceinline__ void gload_lds16(const bf16_t* g, bf16_t* l) {
  auto gp = reinterpret_cast<const __attribute__((address_space(1))) char*>(
      reinterpret_cast<uintptr_t>(g));
  auto lp = reinterpret_cast<__attribute__((address_space(3))) char*>(
      reinterpret_cast<uintptr_t>(l));
  __builtin_amdgcn_global_load_lds(gp, lp, 16, 0, 0);
}

enum { EPI_T_POS = 0, EPI_BF16 = 1, EPI_ADD_T = 2, EPI_GELU = 3, EPI_F32 = 4 };

// ============================================================================
// gemm3: C = A(MxK,bf16) @ Bt(NxK,bf16)^T
// 128x128 tile, BK=64, 256 thr (4 waves, 2x2 wave grid, 64x64 per wave).
// Ring-2 LDS (64KB -> 2 blocks/CU), 2-phase: stage(next) -> compute(cur) ->
// __syncthreads(). Swizzled LDS (slot ^= row&7, both-sides). T1 XCD swizzle.
// Frag reads: 4 base vaddrs + compile-time immediates (buffer via unroll-by-2).
// ============================================================================
template <int EPI>
__global__ __launch_bounds__(256, 2) void gemm3_kernel(
    const bf16_t* __restrict__ A, const bf16_t* __restrict__ Bt,
    const float* __restrict__ bias, float* __restrict__ fout,
    bf16_t* __restrict__ bout, const float* __restrict__ pos,
    int M, int N, int K, int mtiles, int nwg)
{
  extern __shared__ bf16_t lds[];    // [2][A:128*64][B:128*64] = 65536 B
  const int tid = threadIdx.x, wave = tid >> 6, lane = tid & 63;
  const int wr = wave >> 1, wc = wave & 1;

  // T1: bijective XCD swizzle (m204)
  int id = blockIdx.x;
  {
    const int q = nwg >> 3, r = nwg & 7;
    const int xcd = id & 7, ix = id >> 3;
    id = (xcd < r ? xcd * (q + 1) : r * (q + 1) + (xcd - r) * q) + ix;
  }
  const int row0 = (id % mtiles) * 128;
  const int col0 = (id / mtiles) * 128;
  const int NT = K >> 6;

  // ---- staging constants: thread -> (row = c*32 + tid>>3, physslot = tid&7)
  const int srow = tid >> 3;                         // 0..31
  const int sswz = ((tid & 7) ^ (srow & 7)) * 8;     // inverse-swizzled src col
  const bf16_t* aptr[4];
  const bf16_t* bptr[4];
  #pragma unroll
  for (int c = 0; c < 4; ++c) {
    int ar = row0 + c * 32 + srow; if (ar > M - 1) ar = M - 1;
    int br = col0 + c * 32 + srow; if (br > N - 1) br = N - 1;
    aptr[c] = A  + (size_t)ar * K + sswz;
    bptr[c] = Bt + (size_t)br * K + sswz;
  }
  bf16_t* sdst = lds + tid * 8;      // + buf*16384 + c*2048 (+8192 for B)

  #define STAGE(BUF, KT) do {                                         \
    const int koff_ = (KT) << 6;                                      \
    _Pragma("unroll")                                                 \
    for (int c_ = 0; c_ < 4; ++c_) {                                  \
      gload_lds16(aptr[c_] + koff_, sdst + (BUF)*16384 + c_*2048);    \
      gload_lds16(bptr[c_] + koff_, sdst + (BUF)*16384 + 8192 + c_*2048); \
    }                                                                 \
  } while (0)

  // ---- fragment-read base addresses (elements)
  const int l15 = lane & 15, l4 = lane >> 4, x7 = l15 & 7;
  const bf16_t* lA0 = lds + (wr * 64 + l15) * 64 + ((l4    ) ^ x7) * 8;
  const bf16_t* lA1 = lds + (wr * 64 + l15) * 64 + ((l4 + 4) ^ x7) * 8;
  const bf16_t* lB0 = lds + 8192 + (wc * 64 + l15) * 64 + ((l4    ) ^ x7) * 8;
  const bf16_t* lB1 = lds + 8192 + (wc * 64 + l15) * 64 + ((l4 + 4) ^ x7) * 8;

  f32x4 acc[4][4] = {};

  #define COMPUTE(BUF) do {                                           \
    bf16x8 fa[4], fb[4];                                              \
    _Pragma("unroll")                                                 \
    for (int m_ = 0; m_ < 4; ++m_) fa[m_] = *(const bf16x8*)(lA0 + (BUF)*16384 + m_*1024); \
    _Pragma("unroll")                                                 \
    for (int n_ = 0; n_ < 4; ++n_) fb[n_] = *(const bf16x8*)(lB0 + (BUF)*16384 + n_*1024); \
    _Pragma("unroll")                                                 \
    for (int m_ = 0; m_ < 4; ++m_)                                    \
      _Pragma("unroll")                                               \
      for (int n_ = 0; n_ < 4; ++n_)                                  \
        acc[m_][n_] = __builtin_amdgcn_mfma_f32_16x16x32_bf16(fa[m_], fb[n_], acc[m_][n_], 0, 0, 0); \
    _Pragma("unroll")                                                 \
    for (int m_ = 0; m_ < 4; ++m_) fa[m_] = *(const bf16x8*)(lA1 + (BUF)*16384 + m_*1024); \
    _Pragma("unroll")                                                 \
    for (int n_ = 0; n_ < 4; ++n_) fb[n_] = *(const bf16x8*)(lB1 + (BUF)*16384 + n_*1024); \
    _Pragma("unroll")                                                 \
    for (int m_ = 0; m_ < 4; ++m_)                                    \
      _Pragma("unroll")                                               \
      for (int n_ = 0; n_ < 4; ++n_)                                  \
        acc[m_][n_] = __builtin_amdgcn_mfma_f32_16x16x32_bf16(fa[m_], fb[n_], acc[m_][n_], 0, 0, 0); \
  } while (0)

  // ---- 2-phase main loop ----
  STAGE(0, 0);
  __syncthreads();
  int kt = 0;
  while (kt + 2 <= NT) {
    if (kt + 1 < NT) STAGE(1, kt + 1);
    COMPUTE(0);
    __syncthreads();
    if (kt + 2 < NT) STAGE(0, kt + 2);
    COMPUTE(1);
    __syncthreads();
    kt += 2;
  }
  if (kt < NT) COMPUTE(0);
  #undef STAGE
  #undef COMPUTE

  // ---- epilogue: D row = (lane>>4)*4 + r, col = lane&15 (m89 layout) ----
  const int rgrp = lane >> 4;
  #pragma unroll
  for (int m = 0; m < 4; ++m) {
    #pragma unroll
    for (int n = 0; n < 4; ++n) {
      const int col = col0 + wc * 64 + n * 16 + l15;
      if (col >= N) continue;
      const int rbase = row0 + wr * 64 + m * 16 + rgrp * 4;
      float bv = 0.f;
      if constexpr (EPI != EPI_F32) bv = bias[col];
      #pragma unroll
      for (int r = 0; r < 4; ++r) {
        const int rr = rbase + r;
        if (rr >= M) continue;
        const float v = acc[m][n][r] + bv;
        const size_t o = (size_t)rr * N + col;
        if constexpr (EPI == EPI_T_POS) {
          const int l = rr % LLEN;
          fout[o] = v + pos[(size_t)l * N + col];
        } else if constexpr (EPI == EPI_BF16) {
          bout[o] = (bf16_t)v;
        } else if constexpr (EPI == EPI_ADD_T) {
          fout[o] += v;
        } else if constexpr (EPI == EPI_GELU) {
          const float gg = 0.5f * v * (1.f + erff(v * 0.70710678118654752f));
          bout[o] = (bf16_t)gg;
        } else {
          fout[o] = v;
        }
      }
    }
  }
}

// ---------------- head GEMM (N=100), simple 128x128 ----------------
__global__ __launch_bounds__(256) void gemm128_f32(
    const bf16_t* __restrict__ A, const bf16_t* __restrict__ Bt,
    float* __restrict__ fout, int M, int N, int K)
{
  __shared__ bf16_t As[128 * 32];
  __shared__ bf16_t Bs[128 * 32];
  const int tid = threadIdx.x, wave = tid >> 6, lane = tid & 63;
  const int row0 = blockIdx.x * 128, col0 = blockIdx.y * 128;
  const int wr = wave >> 1, wc = wave & 1;
  f32x4 acc[4][4] = {};
  const int srow = lane >> 2, skoff = (lane & 3) * 8;
  const int nsteps = K >> 5;
  for (int kt = 0; kt < nsteps; ++kt) {
    const int k0 = kt << 5;
    #pragma unroll
    for (int i = 0; i < 2; ++i) {
      const int r = (i * 4 + wave) * 16 + srow;
      int arow = row0 + r; if (arow > M - 1) arow = M - 1;
      int brow = col0 + r; if (brow > N - 1) brow = N - 1;
      gload_lds16(A  + (size_t)arow * K + k0 + skoff, &As[r * 32 + skoff]);
      gload_lds16(Bt + (size_t)brow * K + k0 + skoff, &Bs[r * 32 + skoff]);
    }
    asm volatile("s_waitcnt vmcnt(0)" ::: "memory");
    __syncthreads();
    const int lrow = lane & 15, lk = (lane >> 4) * 8;
    bf16x8 af[4], bfr[4];
    #pragma unroll
    for (int mi = 0; mi < 4; ++mi)
      af[mi] = *(const bf16x8*)&As[(wr * 64 + mi * 16 + lrow) * 32 + lk];
    #pragma unroll
    for (int ni = 0; ni < 4; ++ni)
      bfr[ni] = *(const bf16x8*)&Bs[(wc * 64 + ni * 16 + lrow) * 32 + lk];
    #pragma unroll
    for (int mi = 0; mi < 4; ++mi)
      #pragma unroll
      for (int ni = 0; ni < 4; ++ni)
        acc[mi][ni] = __builtin_amdgcn_mfma_f32_16x16x32_bf16(af[mi], bfr[ni], acc[mi][ni], 0, 0, 0);
    __syncthreads();
  }
  const int lcol = lane & 15, rgrp = lane >> 4;
  #pragma unroll
  for (int mi = 0; mi < 4; ++mi)
    #pragma unroll
    for (int ni = 0; ni < 4; ++ni) {
      const int col = col0 + wc * 64 + ni * 16 + lcol;
      if (col >= N) continue;
      const int rbase = row0 + wr * 64 + mi * 16 + rgrp * 4;
      #pragma unroll
      for (int r = 0; r < 4; ++r) {
        const int rr = rbase + r;
        if (rr >= M) continue;
        fout[(size_t)rr * N + col] = acc[mi][ni][r];
      }
    }
}

// ---------------- LayerNorm: one wave per token, E=768 ----------------
__global__ __launch_bounds__(256) void ln_kernel(
    const float* __restrict__ t, const float* __restrict__ w,
    const float* __restrict__ b, bf16_t* __restrict__ y)
{
  const int token = blockIdx.x * 4 + (threadIdx.x >> 6);
  const int lane  = threadIdx.x & 63;
  const float* xp = t + (size_t)token * EDIM;
  float v[12];
  float s = 0.f;
  #pragma unroll
  for (int i = 0; i < 12; ++i) { v[i] = xp[lane + i * 64]; s += v[i]; }
  #pragma unroll
  for (int off = 32; off; off >>= 1) s += __shfl_xor(s, off);
  const float mu = s * (1.f / 768.f);
  float q = 0.f;
  #pragma unroll
  for (int i = 0; i < 12; ++i) { const float d = v[i] - mu; q += d * d; }
  #pragma unroll
  for (int off = 32; off; off >>= 1) q += __shfl_xor(q, off);
  const float rs = rsqrtf(q * (1.f / 768.f) + 1e-6f);
  bf16_t* yp = y + (size_t)token * EDIM;
  #pragma unroll
  for (int i = 0; i < 12; ++i) {
    const int e = lane + i * 64;
    yp[e] = (bf16_t)((v[i] - mu) * rs * w[e] + b[e]);
  }
}

// ---------------- row-wise attention: block per (b_local, s1, h) -----------
__global__ __launch_bounds__(256) void attn_kernel(
    const bf16_t* __restrict__ qkv, bf16_t* __restrict__ o)
{
  const int blk = blockIdx.x;
  const int h  = blk % 12;
  const int bs = blk / 12;
  const int s1 = bs % SDIM;
  const int b  = bs / SDIM;
  __shared__ float Qs[SDIM][65], Ks[SDIM][65], Vs[SDIM][65], Ps[SDIM][42];
  const int tid = threadIdx.x;
  const size_t base = ((size_t)b * LLEN + (size_t)s1 * SDIM);

  for (int idx = tid; idx < SDIM * 64; idx += 256) {
    const int m = idx >> 6, d = idx & 63;
    const bf16_t* p = qkv + (base + m) * 2304 + h * 64 + d;
    Qs[m][d] = (float)p[0];
    Ks[m][d] = (float)p[768];
    Vs[m][d] = (float)p[1536];
  }
  __syncthreads();

  for (int idx = tid; idx < SDIM * SDIM; idx += 256) {
    const int n = idx / SDIM, m = idx % SDIM;
    float s = 0.f;
    #pragma unroll
    for (int d = 0; d < 64; ++d) s += Qs[n][d] * Ks[m][d];
    Ps[n][m] = s * 0.125f;
  }
  __syncthreads();

  if (tid < SDIM) {
    float mx = -1e30f;
    for (int m = 0; m < SDIM; ++m) mx = fmaxf(mx, Ps[tid][m]);
    float sum = 0.f;
    for (int m = 0; m < SDIM; ++m) { const float e = __expf(Ps[tid][m] - mx); Ps[tid][m] = e; sum += e; }
    const float inv = 1.f / sum;
    for (int m = 0; m < SDIM; ++m) Ps[tid][m] *= inv;
  }
  __syncthreads();

  for (int idx = tid; idx < SDIM * 64; idx += 256) {
    const int n = idx >> 6, d = idx & 63;
    float s = 0.f;
    #pragma unroll
    for (int m = 0; m < SDIM; ++m) s += Ps[n][m] * Vs[m][d];
    o[(base + n) * EDIM + h * 64 + d] = (bf16_t)s;
  }
}

// ---------------- transpose fp32(KxN) -> bf16(NxK) ----------------
__global__ __launch_bounds__(256) void transpose_kernel(
    const float* __restrict__ in, bf16_t* __restrict__ out, int K, int N)
{
  __shared__ float tile[32][33];
  const int k0 = blockIdx.x * 32, n0 = blockIdx.y * 32;
  const int tx = threadIdx.x & 31, ty = threadIdx.x >> 5;
  #pragma unroll
  for (int i = 0; i < 32; i += 8) {
    const int k = k0 + ty + i, n = n0 + tx;
    if (k < K && n < N) tile[ty + i][tx] = in[(size_t)k * N + n];
  }
  __syncthreads();
  #pragma unroll
  for (int i = 0; i < 32; i += 8) {
    const int n = n0 + ty + i, k = k0 + tx;
    if (n < N && k < K) out[(size_t)n * K + k] = (bf16_t)tile[tx][ty + i];
  }
}

// ---------------- im2col for conv1 chunk (pad K 1200->1216) ----------------
__global__ __launch_bounds__(256) void im2col_kernel(
    const float* __restrict__ x, bf16_t* __restrict__ col, int tok0, int ntok)
{
  const size_t idx = (size_t)blockIdx.x * 256 + threadIdx.x;
  if (idx >= (size_t)ntok * 1216) return;
  const int kk = (int)(idx % 1216);
  const size_t tok = tok0 + idx / 1216;
  const int b = (int)(tok / LLEN), l = (int)(tok % LLEN);
  const int s1 = l / SDIM, s2 = l % SDIM;
  float v = 0.f;
  if (kk < 1200) {
    const int cin = kk / 100, r = kk % 100, ky = r / 10, kx = r % 10;
    const int iy = s1 - 5 + ky, ix = s2 - 5 + kx;
    if (iy >= 0 && iy < 40 && ix >= 0 && ix < 40)
      v = x[((size_t)(b * 12 + cin) * 40 + iy) * 40 + ix];
  }
  col[idx] = (bf16_t)v;
}

__global__ __launch_bounds__(256) void convw_kernel(
    const float* __restrict__ w, bf16_t* __restrict__ out)
{
  const int idx = blockIdx.x * 256 + threadIdx.x;
  const int kk = idx % 1216, e = idx / 1216;
  const float v = (kk < 1200) ? w[(size_t)e * 1200 + kk] : 0.f;
  out[idx] = (bf16_t)v;
}

__global__ __launch_bounds__(256) void tconvw_kernel(
    const float* __restrict__ w, bf16_t* __restrict__ out)
{
  const int idx = blockIdx.x * 256 + threadIdx.x;  // 100*768
  const int e = idx % 768, tap = idx / 768;
  const int ky = tap / 10, kx = tap % 10;
  out[idx] = (bf16_t)w[(size_t)e * 100 + (9 - ky) * 10 + (9 - kx)];
}

// ---------------- final gather ----------------
__global__ __launch_bounds__(256) void outconv_kernel(
    const float* __restrict__ g, const float* __restrict__ tb,
    float* __restrict__ out)
{
  const int idx = blockIdx.x * 256 + threadIdx.x;
  if (idx >= 16 * 40 * 40) return;
  const int x = idx % 40, y = (idx / 40) % 40, b = idx / 1600;
  float s = tb[0];
  #pragma unroll
  for (int ky = 0; ky < 10; ++ky) {
    const int ty_ = y - 4 + ky;
    if (ty_ < 0 || ty_ >= SDIM) continue;
    #pragma unroll
    for (int kx = 0; kx < 10; ++kx) {
      const int tx_ = x - 4 + kx;
      if (tx_ < 0 || tx_ >= SDIM) continue;
      s += g[((size_t)b * LLEN + ty_ * SDIM + tx_) * 100 + ky * 10 + kx];
    }
  }
  out[idx] = s;
}

// ============================================================================
extern "C" void kernel_launch(void* const* d_in, const int* in_sizes, int n_in,
                              void* d_out, int out_size, void* d_ws, size_t ws_size,
                              hipStream_t stream)
{
  const float* x       = (const float*)d_in[0];
  const float* conv_w  = (const float*)d_in[1];
  const float* conv_b  = (const float*)d_in[2];
  const float* pos     = (const float*)d_in[3];
  const float* ln1_w   = (const float*)d_in[4];
  const float* ln1_b   = (const float*)d_in[5];
  const float* qkv_w   = (const float*)d_in[6];
  const float* qkv_b   = (const float*)d_in[7];
  const float* proj_w  = (const float*)d_in[8];
  const float* proj_b  = (const float*)d_in[9];
  const float* ln2_w   = (const float*)d_in[10];
  const float* ln2_b   = (const float*)d_in[11];
  const float* fc1_w   = (const float*)d_in[12];
  const float* fc1_b   = (const float*)d_in[13];
  const float* fc2_w   = (const float*)d_in[14];
  const float* fc2_b   = (const float*)d_in[15];
  const float* lnf_w   = (const float*)d_in[16];
  const float* lnf_b   = (const float*)d_in[17];
  const float* tconv_w = (const float*)d_in[18];
  const float* tconv_b = (const float*)d_in[19];
  float* out = (float*)d_out;

  constexpr int LDS3 = 65536;  // 2 x (128x64 A + 128x64 B) bf16
  hipFuncSetAttribute((const void*)gemm3_kernel<EPI_T_POS>, hipFuncAttributeMaxDynamicSharedMemorySize, LDS3);
  hipFuncSetAttribute((const void*)gemm3_kernel<EPI_BF16 >, hipFuncAttributeMaxDynamicSharedMemorySize, LDS3);
  hipFuncSetAttribute((const void*)gemm3_kernel<EPI_ADD_T>, hipFuncAttributeMaxDynamicSharedMemorySize, LDS3);
  hipFuncSetAttribute((const void*)gemm3_kernel<EPI_GELU >, hipFuncAttributeMaxDynamicSharedMemorySize, LDS3);

  // ---- workspace: pick chunking from ws_size ----
  const size_t need2 = 14155776UL + 82624512UL + 41312256UL + 82624512UL + 2048UL;
  const int nch = (ws_size >= need2) ? 2 : 4;
  const int cht = TOKENS / nch;          // 13448 or 6724

  char* p = (char*)d_ws;
  auto alloc = [&](size_t bytes) {
    char* r = p;
    p += (bytes + 255) & ~(size_t)255;
    return r;
  };
  bf16_t* wbuf = (bf16_t*)alloc((size_t)768 * 9216 * 2);
  float*  t    = (float*)alloc((size_t)TOKENS * EDIM * 4);
  bf16_t* ybuf = (bf16_t*)alloc((size_t)TOKENS * EDIM * 2);
  bf16_t* hbuf = (bf16_t*)alloc((size_t)cht * 3072 * 2);

  bf16_t* Wq = wbuf;
  bf16_t* Wp = Wq + (size_t)2304 * 768;
  bf16_t* W1 = Wp + (size_t)768 * 768;
  bf16_t* W2 = W1 + (size_t)3072 * 768;

  auto g3 = [&](int epi, const bf16_t* A, const bf16_t* Bt,
                const float* bias, float* fo, bf16_t* bo, const float* pe,
                int M, int N, int K) {
    const int mtiles = (M + 127) / 128;
    const int nwg = mtiles * (N / 128);
    switch (epi) {
      case EPI_T_POS: gemm3_kernel<EPI_T_POS><<<nwg, 256, LDS3, stream>>>(A, Bt, bias, fo, bo, pe, M, N, K, mtiles, nwg); break;
      case EPI_BF16:  gemm3_kernel<EPI_BF16 ><<<nwg, 256, LDS3, stream>>>(A, Bt, bias, fo, bo, pe, M, N, K, mtiles, nwg); break;
      case EPI_ADD_T: gemm3_kernel<EPI_ADD_T><<<nwg, 256, LDS3, stream>>>(A, Bt, bias, fo, bo, pe, M, N, K, mtiles, nwg); break;
      default:        gemm3_kernel<EPI_GELU ><<<nwg, 256, LDS3, stream>>>(A, Bt, bias, fo, bo, pe, M, N, K, mtiles, nwg); break;
    }
  };

  // ---- conv1 as chunked im2col GEMM -> t (+bias +pos_embed) ----
  convw_kernel<<<(768 * 1216) / 256, 256, 0, stream>>>(conv_w, wbuf);
  for (int c = 0; c < nch; ++c) {
    const int tok0 = c * cht;
    im2col_kernel<<<(unsigned)(((size_t)cht * 1216 + 255) / 256), 256, 0, stream>>>(x, hbuf, tok0, cht);
    g3(EPI_T_POS, hbuf, wbuf, conv_b, t + (size_t)tok0 * EDIM, nullptr, pos, cht, EDIM, 1216);
  }

  // ---- transformer layers ----
  for (int i = 0; i < 12; ++i) {
    transpose_kernel<<<dim3(24, 72), 256, 0, stream>>>(qkv_w + (size_t)i * 768 * 2304, Wq, 768, 2304);
    transpose_kernel<<<dim3(24, 24), 256, 0, stream>>>(proj_w + (size_t)i * 768 * 768, Wp, 768, 768);
    transpose_kernel<<<dim3(24, 96), 256, 0, stream>>>(fc1_w + (size_t)i * 768 * 3072, W1, 768, 3072);
    transpose_kernel<<<dim3(96, 24), 256, 0, stream>>>(fc2_w + (size_t)i * 3072 * 768, W2, 3072, 768);

    ln_kernel<<<TOKENS / 4, 256, 0, stream>>>(t, ln1_w + i * EDIM, ln1_b + i * EDIM, ybuf);
    for (int c = 0; c < nch; ++c) {
      const size_t ro = (size_t)c * cht;
      g3(EPI_BF16, ybuf + ro * EDIM, Wq, qkv_b + i * 2304, nullptr, hbuf, nullptr, cht, 2304, 768);
      attn_kernel<<<(16 / nch) * SDIM * 12, 256, 0, stream>>>(hbuf, ybuf + ro * EDIM);
    }
    g3(EPI_ADD_T, ybuf, Wp, proj_b + i * EDIM, t, nullptr, nullptr, TOKENS, EDIM, 768);

    ln_kernel<<<TOKENS / 4, 256, 0, stream>>>(t, ln2_w + i * EDIM, ln2_b + i * EDIM, ybuf);
    for (int c = 0; c < nch; ++c) {
      const size_t ro = (size_t)c * cht;
      g3(EPI_GELU, ybuf + ro * EDIM, W1, fc1_b + i * 3072, nullptr, hbuf, nullptr, cht, 3072, 768);
      g3(EPI_ADD_T, hbuf, W2, fc2_b + i * EDIM, t + ro * EDIM, nullptr, nullptr, cht, EDIM, 3072);
    }
  }

  // ---- final LN + tconv head ----
  ln_kernel<<<TOKENS / 4, 256, 0, stream>>>(t, lnf_w, lnf_b, ybuf);
  tconvw_kernel<<<(100 * 768) / 256, 256, 0, stream>>>(tconv_w, wbuf);
  gemm128_f32<<<dim3((TOKENS + 127) / 128, 1), 256, 0, stream>>>(ybuf, wbuf, (float*)hbuf, TOKENS, 100, 768);
  outconv_kernel<<<100, 256, 0, stream>>>((const float*)hbuf, tconv_b, out);
}

// Round 5
// 11459.093 us; speedup vs baseline: 1.4576x; 1.2274x over previous
//
#include <hip/hip_runtime.h>
#include <cstdint>

typedef __bf16 bf16_t;
typedef __attribute__((ext_vector_type(8))) __bf16 bf16x8;
typedef __attribute__((ext_vector_type(4))) float f32x4;

#define TOKENS 26896
#define LLEN   1681
#define SDIM   41
#define EDIM   768

// ---------------- async global->LDS 16B ----------------
__device__ __forceinline__ void gload_lds16(const bf16_t* g, bf16_t* l) {
  auto gp = reinterpret_cast<const __attribute__((address_space(1))) char*>(
      reinterpret_cast<uintptr_t>(g));
  auto lp = reinterpret_cast<__attribute__((address_space(3))) char*>(
      reinterpret_cast<uintptr_t>(l));
  __builtin_amdgcn_global_load_lds(gp, lp, 16, 0, 0);
}

enum { EPI_T_POS = 0, EPI_BF16 = 1, EPI_ADD_T = 2, EPI_GELU = 3, EPI_F32 = 4 };

// ============================================================================
// gemm4: C = A(MxK,bf16) @ Bt(NxK,bf16)^T
// 128x128 tile, BK=32, 256 thr (2x2 waves, 64x64 per wave).
// Ring-2 LDS in 32KB static -> 4 blocks/CU (16 waves/CU): barrier drains of one
// block overlap other blocks' MFMA (m97/m114 mechanism).
// Row-major tile order (A-panel L2 reuse) + XCD chunked swizzle.
// Swizzled LDS (phys_slot = k_slot ^ ((row>>1)&3), both sides; 0 conflicts
// measured in round 3). Frag reads: base + compile-time immediates.
// ============================================================================
template <int EPI>
__global__ __launch_bounds__(256, 4) void gemm4_kernel(
    const bf16_t* __restrict__ A, const bf16_t* __restrict__ Bt,
    const float* __restrict__ bias, float* __restrict__ fout,
    bf16_t* __restrict__ bout, const float* __restrict__ pos,
    int M, int N, int K, int ntn, int nwg)
{
  __shared__ bf16_t lds[16384];      // [2 bufs][A:128x32][B:128x32]
  const int tid = threadIdx.x, wave = tid >> 6, lane = tid & 63;
  const int wr = wave >> 1, wc = wave & 1;

  // T1: bijective XCD chunked swizzle (m204)
  int id = blockIdx.x;
  {
    const int q = nwg >> 3, r = nwg & 7;
    const int xcd = id & 7, ix = id >> 3;
    id = (xcd < r ? xcd * (q + 1) : r * (q + 1) + (xcd - r) * q) + ix;
  }
  const int row0 = (id / ntn) * 128;   // row-major over col-tiles: A reuse
  const int col0 = (id % ntn) * 128;
  const int NT = K >> 5;

  // ---- staging: thread -> (row = p*64 + tid>>2, phys slot = tid&3)
  const int srow = tid >> 2;                                  // 0..63
  const int sswz = ((tid & 3) ^ ((srow >> 1) & 3)) * 8;       // logical src col
  const bf16_t* aptr[2];
  const bf16_t* bptr[2];
  #pragma unroll
  for (int p = 0; p < 2; ++p) {
    int ar = row0 + p * 64 + srow; if (ar > M - 1) ar = M - 1;
    int br = col0 + p * 64 + srow; if (br > N - 1) br = N - 1;
    aptr[p] = A  + (size_t)ar * K + sswz;   // ((r>>1)&3) same for p=0/1 (r+64)
    bptr[p] = Bt + (size_t)br * K + sswz;
  }
  bf16_t* sdst = lds + tid * 8;  // dest elem = 8*tid (linear per lane)

  #define STAGE(BUF, KT) do {                                   \
    const int koff_ = (KT) << 5;                                \
    gload_lds16(aptr[0] + koff_, sdst + (BUF)*8192);            \
    gload_lds16(aptr[1] + koff_, sdst + (BUF)*8192 + 2048);     \
    gload_lds16(bptr[0] + koff_, sdst + (BUF)*8192 + 4096);     \
    gload_lds16(bptr[1] + koff_, sdst + (BUF)*8192 + 6144);     \
  } while (0)

  // ---- fragment bases: row = {wr,wc}*64 + m*16 + l15; (row>>1)&3 == (l15>>1)&3
  const int l15 = lane & 15, l4 = lane >> 4;
  const int fswz = (l4 ^ ((l15 >> 1) & 3)) << 3;
  const bf16_t* lA = lds + (wr * 64 + l15) * 32 + fswz;
  const bf16_t* lB = lds + 4096 + (wc * 64 + l15) * 32 + fswz;

  f32x4 acc[4][4] = {};

  #define COMPUTE(BUF) do {                                     \
    bf16x8 fa[4], fb[4];                                        \
    _Pragma("unroll")                                           \
    for (int m_ = 0; m_ < 4; ++m_) fa[m_] = *(const bf16x8*)(lA + (BUF)*8192 + m_*512); \
    _Pragma("unroll")                                           \
    for (int n_ = 0; n_ < 4; ++n_) fb[n_] = *(const bf16x8*)(lB + (BUF)*8192 + n_*512); \
    _Pragma("unroll")                                           \
    for (int m_ = 0; m_ < 4; ++m_)                              \
      _Pragma("unroll")                                         \
      for (int n_ = 0; n_ < 4; ++n_)                            \
        acc[m_][n_] = __builtin_amdgcn_mfma_f32_16x16x32_bf16(fa[m_], fb[n_], acc[m_][n_], 0, 0, 0); \
  } while (0)

  // ---- 2-phase main loop (NT is even for all shapes used) ----
  STAGE(0, 0);
  __syncthreads();
  int kt = 0;
  while (kt + 2 <= NT) {
    if (kt + 1 < NT) STAGE(1, kt + 1);
    COMPUTE(0);
    __syncthreads();
    if (kt + 2 < NT) STAGE(0, kt + 2);
    COMPUTE(1);
    __syncthreads();
    kt += 2;
  }
  if (kt < NT) COMPUTE(0);
  #undef STAGE
  #undef COMPUTE

  // ---- epilogue: D row = (lane>>4)*4 + r, col = lane&15 (m89 layout) ----
  const int rgrp = lane >> 4;
  #pragma unroll
  for (int m = 0; m < 4; ++m) {
    #pragma unroll
    for (int n = 0; n < 4; ++n) {
      const int col = col0 + wc * 64 + n * 16 + l15;
      if (col >= N) continue;
      const int rbase = row0 + wr * 64 + m * 16 + rgrp * 4;
      float bv = 0.f;
      if constexpr (EPI != EPI_F32) bv = bias[col];
      #pragma unroll
      for (int r = 0; r < 4; ++r) {
        const int rr = rbase + r;
        if (rr >= M) continue;
        const float v = acc[m][n][r] + bv;
        const size_t o = (size_t)rr * N + col;
        if constexpr (EPI == EPI_T_POS) {
          const int l = rr % LLEN;
          fout[o] = v + pos[(size_t)l * N + col];
        } else if constexpr (EPI == EPI_BF16) {
          bout[o] = (bf16_t)v;
        } else if constexpr (EPI == EPI_ADD_T) {
          fout[o] += v;
        } else if constexpr (EPI == EPI_GELU) {
          const float gg = 0.5f * v * (1.f + erff(v * 0.70710678118654752f));
          bout[o] = (bf16_t)gg;
        } else {
          fout[o] = v;
        }
      }
    }
  }
}

// ---------------- head GEMM (N=100), simple 128x128 ----------------
__global__ __launch_bounds__(256) void gemm128_f32(
    const bf16_t* __restrict__ A, const bf16_t* __restrict__ Bt,
    float* __restrict__ fout, int M, int N, int K)
{
  __shared__ bf16_t As[128 * 32];
  __shared__ bf16_t Bs[128 * 32];
  const int tid = threadIdx.x, wave = tid >> 6, lane = tid & 63;
  const int row0 = blockIdx.x * 128, col0 = blockIdx.y * 128;
  const int wr = wave >> 1, wc = wave & 1;
  f32x4 acc[4][4] = {};
  const int srow = lane >> 2, skoff = (lane & 3) * 8;
  const int nsteps = K >> 5;
  for (int kt = 0; kt < nsteps; ++kt) {
    const int k0 = kt << 5;
    #pragma unroll
    for (int i = 0; i < 2; ++i) {
      const int r = (i * 4 + wave) * 16 + srow;
      int arow = row0 + r; if (arow > M - 1) arow = M - 1;
      int brow = col0 + r; if (brow > N - 1) brow = N - 1;
      gload_lds16(A  + (size_t)arow * K + k0 + skoff, &As[r * 32 + skoff]);
      gload_lds16(Bt + (size_t)brow * K + k0 + skoff, &Bs[r * 32 + skoff]);
    }
    asm volatile("s_waitcnt vmcnt(0)" ::: "memory");
    __syncthreads();
    const int lrow = lane & 15, lk = (lane >> 4) * 8;
    bf16x8 af[4], bfr[4];
    #pragma unroll
    for (int mi = 0; mi < 4; ++mi)
      af[mi] = *(const bf16x8*)&As[(wr * 64 + mi * 16 + lrow) * 32 + lk];
    #pragma unroll
    for (int ni = 0; ni < 4; ++ni)
      bfr[ni] = *(const bf16x8*)&Bs[(wc * 64 + ni * 16 + lrow) * 32 + lk];
    #pragma unroll
    for (int mi = 0; mi < 4; ++mi)
      #pragma unroll
      for (int ni = 0; ni < 4; ++ni)
        acc[mi][ni] = __builtin_amdgcn_mfma_f32_16x16x32_bf16(af[mi], bfr[ni], acc[mi][ni], 0, 0, 0);
    __syncthreads();
  }
  const int lcol = lane & 15, rgrp = lane >> 4;
  #pragma unroll
  for (int mi = 0; mi < 4; ++mi)
    #pragma unroll
    for (int ni = 0; ni < 4; ++ni) {
      const int col = col0 + wc * 64 + ni * 16 + lcol;
      if (col >= N) continue;
      const int rbase = row0 + wr * 64 + mi * 16 + rgrp * 4;
      #pragma unroll
      for (int r = 0; r < 4; ++r) {
        const int rr = rbase + r;
        if (rr >= M) continue;
        fout[(size_t)rr * N + col] = acc[mi][ni][r];
      }
    }
}

// ---------------- LayerNorm: one wave per token, E=768 ----------------
__global__ __launch_bounds__(256) void ln_kernel(
    const float* __restrict__ t, const float* __restrict__ w,
    const float* __restrict__ b, bf16_t* __restrict__ y)
{
  const int token = blockIdx.x * 4 + (threadIdx.x >> 6);
  const int lane  = threadIdx.x & 63;
  const float* xp = t + (size_t)token * EDIM;
  float v[12];
  float s = 0.f;
  #pragma unroll
  for (int i = 0; i < 12; ++i) { v[i] = xp[lane + i * 64]; s += v[i]; }
  #pragma unroll
  for (int off = 32; off; off >>= 1) s += __shfl_xor(s, off);
  const float mu = s * (1.f / 768.f);
  float q = 0.f;
  #pragma unroll
  for (int i = 0; i < 12; ++i) { const float d = v[i] - mu; q += d * d; }
  #pragma unroll
  for (int off = 32; off; off >>= 1) q += __shfl_xor(q, off);
  const float rs = rsqrtf(q * (1.f / 768.f) + 1e-6f);
  bf16_t* yp = y + (size_t)token * EDIM;
  #pragma unroll
  for (int i = 0; i < 12; ++i) {
    const int e = lane + i * 64;
    yp[e] = (bf16_t)((v[i] - mu) * rs * w[e] + b[e]);
  }
}

// ---------------- row-wise attention: block per (b_local, s1, h) -----------
__global__ __launch_bounds__(256) void attn_kernel(
    const bf16_t* __restrict__ qkv, bf16_t* __restrict__ o)
{
  const int blk = blockIdx.x;
  const int h  = blk % 12;
  const int bs = blk / 12;
  const int s1 = bs % SDIM;
  const int b  = bs / SDIM;
  __shared__ float Qs[SDIM][65], Ks[SDIM][65], Vs[SDIM][65], Ps[SDIM][42];
  const int tid = threadIdx.x;
  const size_t base = ((size_t)b * LLEN + (size_t)s1 * SDIM);

  for (int idx = tid; idx < SDIM * 64; idx += 256) {
    const int m = idx >> 6, d = idx & 63;
    const bf16_t* p = qkv + (base + m) * 2304 + h * 64 + d;
    Qs[m][d] = (float)p[0];
    Ks[m][d] = (float)p[768];
    Vs[m][d] = (float)p[1536];
  }
  __syncthreads();

  for (int idx = tid; idx < SDIM * SDIM; idx += 256) {
    const int n = idx / SDIM, m = idx % SDIM;
    float s = 0.f;
    #pragma unroll
    for (int d = 0; d < 64; ++d) s += Qs[n][d] * Ks[m][d];
    Ps[n][m] = s * 0.125f;
  }
  __syncthreads();

  if (tid < SDIM) {
    float mx = -1e30f;
    for (int m = 0; m < SDIM; ++m) mx = fmaxf(mx, Ps[tid][m]);
    float sum = 0.f;
    for (int m = 0; m < SDIM; ++m) { const float e = __expf(Ps[tid][m] - mx); Ps[tid][m] = e; sum += e; }
    const float inv = 1.f / sum;
    for (int m = 0; m < SDIM; ++m) Ps[tid][m] *= inv;
  }
  __syncthreads();

  for (int idx = tid; idx < SDIM * 64; idx += 256) {
    const int n = idx >> 6, d = idx & 63;
    float s = 0.f;
    #pragma unroll
    for (int m = 0; m < SDIM; ++m) s += Ps[n][m] * Vs[m][d];
    o[(base + n) * EDIM + h * 64 + d] = (bf16_t)s;
  }
}

// ---------------- transpose fp32(KxN) -> bf16(NxK) ----------------
__global__ __launch_bounds__(256) void transpose_kernel(
    const float* __restrict__ in, bf16_t* __restrict__ out, int K, int N)
{
  __shared__ float tile[32][33];
  const int k0 = blockIdx.x * 32, n0 = blockIdx.y * 32;
  const int tx = threadIdx.x & 31, ty = threadIdx.x >> 5;
  #pragma unroll
  for (int i = 0; i < 32; i += 8) {
    const int k = k0 + ty + i, n = n0 + tx;
    if (k < K && n < N) tile[ty + i][tx] = in[(size_t)k * N + n];
  }
  __syncthreads();
  #pragma unroll
  for (int i = 0; i < 32; i += 8) {
    const int n = n0 + ty + i, k = k0 + tx;
    if (n < N && k < K) out[(size_t)n * K + k] = (bf16_t)tile[tx][ty + i];
  }
}

// ---------------- im2col for conv1 chunk (pad K 1200->1216) ----------------
__global__ __launch_bounds__(256) void im2col_kernel(
    const float* __restrict__ x, bf16_t* __restrict__ col, int tok0, int ntok)
{
  const size_t idx = (size_t)blockIdx.x * 256 + threadIdx.x;
  if (idx >= (size_t)ntok * 1216) return;
  const int kk = (int)(idx % 1216);
  const size_t tok = tok0 + idx / 1216;
  const int b = (int)(tok / LLEN), l = (int)(tok % LLEN);
  const int s1 = l / SDIM, s2 = l % SDIM;
  float v = 0.f;
  if (kk < 1200) {
    const int cin = kk / 100, r = kk % 100, ky = r / 10, kx = r % 10;
    const int iy = s1 - 5 + ky, ix = s2 - 5 + kx;
    if (iy >= 0 && iy < 40 && ix >= 0 && ix < 40)
      v = x[((size_t)(b * 12 + cin) * 40 + iy) * 40 + ix];
  }
  col[idx] = (bf16_t)v;
}

__global__ __launch_bounds__(256) void convw_kernel(
    const float* __restrict__ w, bf16_t* __restrict__ out)
{
  const int idx = blockIdx.x * 256 + threadIdx.x;
  const int kk = idx % 1216, e = idx / 1216;
  const float v = (kk < 1200) ? w[(size_t)e * 1200 + kk] : 0.f;
  out[idx] = (bf16_t)v;
}

__global__ __launch_bounds__(256) void tconvw_kernel(
    const float* __restrict__ w, bf16_t* __restrict__ out)
{
  const int idx = blockIdx.x * 256 + threadIdx.x;  // 100*768
  const int e = idx % 768, tap = idx / 768;
  const int ky = tap / 10, kx = tap % 10;
  out[idx] = (bf16_t)w[(size_t)e * 100 + (9 - ky) * 10 + (9 - kx)];
}

// ---------------- final gather ----------------
__global__ __launch_bounds__(256) void outconv_kernel(
    const float* __restrict__ g, const float* __restrict__ tb,
    float* __restrict__ out)
{
  const int idx = blockIdx.x * 256 + threadIdx.x;
  if (idx >= 16 * 40 * 40) return;
  const int x = idx % 40, y = (idx / 40) % 40, b = idx / 1600;
  float s = tb[0];
  #pragma unroll
  for (int ky = 0; ky < 10; ++ky) {
    const int ty_ = y - 4 + ky;
    if (ty_ < 0 || ty_ >= SDIM) continue;
    #pragma unroll
    for (int kx = 0; kx < 10; ++kx) {
      const int tx_ = x - 4 + kx;
      if (tx_ < 0 || tx_ >= SDIM) continue;
      s += g[((size_t)b * LLEN + ty_ * SDIM + tx_) * 100 + ky * 10 + kx];
    }
  }
  out[idx] = s;
}

// ============================================================================
extern "C" void kernel_launch(void* const* d_in, const int* in_sizes, int n_in,
                              void* d_out, int out_size, void* d_ws, size_t ws_size,
                              hipStream_t stream)
{
  const float* x       = (const float*)d_in[0];
  const float* conv_w  = (const float*)d_in[1];
  const float* conv_b  = (const float*)d_in[2];
  const float* pos     = (const float*)d_in[3];
  const float* ln1_w   = (const float*)d_in[4];
  const float* ln1_b   = (const float*)d_in[5];
  const float* qkv_w   = (const float*)d_in[6];
  const float* qkv_b   = (const float*)d_in[7];
  const float* proj_w  = (const float*)d_in[8];
  const float* proj_b  = (const float*)d_in[9];
  const float* ln2_w   = (const float*)d_in[10];
  const float* ln2_b   = (const float*)d_in[11];
  const float* fc1_w   = (const float*)d_in[12];
  const float* fc1_b   = (const float*)d_in[13];
  const float* fc2_w   = (const float*)d_in[14];
  const float* fc2_b   = (const float*)d_in[15];
  const float* lnf_w   = (const float*)d_in[16];
  const float* lnf_b   = (const float*)d_in[17];
  const float* tconv_w = (const float*)d_in[18];
  const float* tconv_b = (const float*)d_in[19];
  float* out = (float*)d_out;

  // ---- workspace: pick chunking from ws_size ----
  const size_t need2 = 14155776UL + 82624512UL + 41312256UL + 82624512UL + 2048UL;
  const int nch = (ws_size >= need2) ? 2 : 4;
  const int cht = TOKENS / nch;          // 13448 or 6724

  char* p = (char*)d_ws;
  auto alloc = [&](size_t bytes) {
    char* r = p;
    p += (bytes + 255) & ~(size_t)255;
    return r;
  };
  bf16_t* wbuf = (bf16_t*)alloc((size_t)768 * 9216 * 2);
  float*  t    = (float*)alloc((size_t)TOKENS * EDIM * 4);
  bf16_t* ybuf = (bf16_t*)alloc((size_t)TOKENS * EDIM * 2);
  bf16_t* hbuf = (bf16_t*)alloc((size_t)cht * 3072 * 2);

  bf16_t* Wq = wbuf;
  bf16_t* Wp = Wq + (size_t)2304 * 768;
  bf16_t* W1 = Wp + (size_t)768 * 768;
  bf16_t* W2 = W1 + (size_t)3072 * 768;

  auto g4 = [&](int epi, const bf16_t* A, const bf16_t* Bt,
                const float* bias, float* fo, bf16_t* bo, const float* pe,
                int M, int N, int K) {
    const int mtiles = (M + 127) / 128;
    const int ntn = N / 128;
    const int nwg = mtiles * ntn;
    switch (epi) {
      case EPI_T_POS: gemm4_kernel<EPI_T_POS><<<nwg, 256, 0, stream>>>(A, Bt, bias, fo, bo, pe, M, N, K, ntn, nwg); break;
      case EPI_BF16:  gemm4_kernel<EPI_BF16 ><<<nwg, 256, 0, stream>>>(A, Bt, bias, fo, bo, pe, M, N, K, ntn, nwg); break;
      case EPI_ADD_T: gemm4_kernel<EPI_ADD_T><<<nwg, 256, 0, stream>>>(A, Bt, bias, fo, bo, pe, M, N, K, ntn, nwg); break;
      default:        gemm4_kernel<EPI_GELU ><<<nwg, 256, 0, stream>>>(A, Bt, bias, fo, bo, pe, M, N, K, ntn, nwg); break;
    }
  };

  // ---- conv1 as chunked im2col GEMM -> t (+bias +pos_embed) ----
  convw_kernel<<<(768 * 1216) / 256, 256, 0, stream>>>(conv_w, wbuf);
  for (int c = 0; c < nch; ++c) {
    const int tok0 = c * cht;
    im2col_kernel<<<(unsigned)(((size_t)cht * 1216 + 255) / 256), 256, 0, stream>>>(x, hbuf, tok0, cht);
    g4(EPI_T_POS, hbuf, wbuf, conv_b, t + (size_t)tok0 * EDIM, nullptr, pos, cht, EDIM, 1216);
  }

  // ---- transformer layers ----
  for (int i = 0; i < 12; ++i) {
    transpose_kernel<<<dim3(24, 72), 256, 0, stream>>>(qkv_w + (size_t)i * 768 * 2304, Wq, 768, 2304);
    transpose_kernel<<<dim3(24, 24), 256, 0, stream>>>(proj_w + (size_t)i * 768 * 768, Wp, 768, 768);
    transpose_kernel<<<dim3(24, 96), 256, 0, stream>>>(fc1_w + (size_t)i * 768 * 3072, W1, 768, 3072);
    transpose_kernel<<<dim3(96, 24), 256, 0, stream>>>(fc2_w + (size_t)i * 3072 * 768, W2, 3072, 768);

    ln_kernel<<<TOKENS / 4, 256, 0, stream>>>(t, ln1_w + i * EDIM, ln1_b + i * EDIM, ybuf);
    for (int c = 0; c < nch; ++c) {
      const size_t ro = (size_t)c * cht;
      g4(EPI_BF16, ybuf + ro * EDIM, Wq, qkv_b + i * 2304, nullptr, hbuf, nullptr, cht, 2304, 768);
      attn_kernel<<<(16 / nch) * SDIM * 12, 256, 0, stream>>>(hbuf, ybuf + ro * EDIM);
    }
    g4(EPI_ADD_T, ybuf, Wp, proj_b + i * EDIM, t, nullptr, nullptr, TOKENS, EDIM, 768);

    ln_kernel<<<TOKENS / 4, 256, 0, stream>>>(t, ln2_w + i * EDIM, ln2_b + i * EDIM, ybuf);
    for (int c = 0; c < nch; ++c) {
      const size_t ro = (size_t)c * cht;
      g4(EPI_GELU, ybuf + ro * EDIM, W1, fc1_b + i * 3072, nullptr, hbuf, nullptr, cht, 3072, 768);
      g4(EPI_ADD_T, hbuf, W2, fc2_b + i * EDIM, t + ro * EDIM, nullptr, nullptr, cht, EDIM, 3072);
    }
  }

  // ---- final LN + tconv head ----
  ln_kernel<<<TOKENS / 4, 256, 0, stream>>>(t, lnf_w, lnf_b, ybuf);
  tconvw_kernel<<<(100 * 768) / 256, 256, 0, stream>>>(tconv_w, wbuf);
  gemm128_f32<<<dim3((TOKENS + 127) / 128, 1), 256, 0, stream>>>(ybuf, wbuf, (float*)hbuf, TOKENS, 100, 768);
  outconv_kernel<<<100, 256, 0, stream>>>((const float*)hbuf, tconv_b, out);
}